// Round 11
// baseline (18897.211 us; speedup 1.0000x reference)
//
#include <hip/hip_runtime.h>
#include <stdint.h>

// SNN LIF multi-layer, B=16384, D_IN=N=512, L=3, T=32 (T hardcoded).
//
// Round 11: round-7 kernel (16 rows x 8 cols/lane, zero-LDS, proven correct)
// with the register budget UNPINNED via __launch_bounds__(256, 1).
//  - pipe model (rounds 5-10): VALU floor 54.6us/GEMM; L1-read need 512/R
//    B/cy (R=16 -> 32 < 64 ok); SALU need 4/C ops/cy (C=8 -> 0.5 < 1 ok).
//    R16/C8 is the only tile with both secondary pipes at <=50% of VALU.
//  - round 7 failed ONLY by VGPR spill at the 128 cap from
//    __launch_bounds__(256,2); ~175 live regs need the (256,1) budget.
//  - FMA chain bit-identical to rounds 1/4/5/7 PASS: fmaf(sm,w,acc), single
//    accumulator per output, k ascending 0..511. Epilogue/masks verbatim
//    from the round-7 PASS.

#define B_SZ 16384
#define N_SZ 512
#define K_SZ 512
#define T_STEPS 32
#define LEAKY 0.9f

// ---------------------------------------------------------------------------
__device__ inline uint32_t mask_word(const unsigned long long bal[8], int lane) {
    const uint32_t sh = (4u * (uint32_t)lane) & 31u;
    uint32_t word = 0;
    #pragma unroll
    for (int j = 0; j < 8; ++j) {
        const uint32_t half = (lane < 8) ? (uint32_t)bal[j] : (uint32_t)(bal[j] >> 32);
        const uint32_t nib  = (half >> sh) & 0xFu;
        word |= ((nib * 0x00204081u) & 0x01010101u) << j;
    }
    return word;
}

// ---------------------------------------------------------------------------
// AMODE: 0 = none, 1 = a := s, 2 = a := a*LEAKY + s
template<int AMODE, bool ADD_U, bool ADD_X1>
__global__ __launch_bounds__(256, 1)
void rowgemm_lif(const uint32_t* __restrict__ mIn,  // [16][B] spike bits
                 const float* __restrict__ Wt,      // [512 k][512 n] = W.T
                 const float* __restrict__ bias,
                 const float* u_prev,               // may alias u_out
                 const float* __restrict__ x1,
                 float* u_out,
                 uint32_t* __restrict__ mOut,       // [16][B] out bits
                 float* a_ptr)
{
    const int lane = threadIdx.x & 63;
    const int w    = threadIdx.x >> 6;
    const int r0   = blockIdx.x * 64 + w * 16;    // 16 rows per wave
    const int cb   = lane * 8;                    // 8-col stripe per lane

    float acc[16][8];
    #pragma unroll
    for (int m = 0; m < 16; ++m)
        #pragma unroll
        for (int j = 0; j < 8; ++j) acc[m][j] = 0.f;

    // W ring, depth 2 k-rows (k and k+1 resident; prefetch k+2,k+3)
    const float* wb = Wt + cb;
    float4 w0a = ((const float4*)wb)[0];
    float4 w0b = ((const float4*)wb)[1];
    float4 w1a = ((const float4*)(wb + 512))[0];
    float4 w1b = ((const float4*)(wb + 512))[1];

    // mask words: lane m holds row r0+m's word for the current chunk
    uint32_t mv = mIn[r0 + (lane & 15)];

    for (int c = 0; c < 16; ++c) {                // 16 chunks of 32 k
        uint32_t ms[16];
        #pragma unroll
        for (int m = 0; m < 16; ++m)
            ms[m] = __builtin_amdgcn_readlane(mv, m);
        {   // prefetch next chunk's masks (dup-load of last chunk is harmless)
            const int cn = (c < 15) ? c + 1 : 15;
            mv = mIn[(size_t)cn * B_SZ + r0 + (lane & 15)];
        }

        #pragma unroll 8
        for (int kp = 0; kp < 16; ++kp) {         // k-pairs within chunk
            const int k = c * 32 + 2 * kp;
            // prefetch k+2, k+3 (last pair overruns by 2 rows -> slack in ws)
            const float* pf = wb + (size_t)(k + 2) * 512;
            const float4 n0a = ((const float4*)pf)[0];
            const float4 n0b = ((const float4*)pf)[1];
            const float4 n1a = ((const float4*)(pf + 512))[0];
            const float4 n1b = ((const float4*)(pf + 512))[1];
            // even k
            #pragma unroll
            for (int m = 0; m < 16; ++m) {
                const float sm = ((ms[m] >> (2 * kp)) & 1u) ? 1.0f : 0.0f;
                acc[m][0] = fmaf(sm, w0a.x, acc[m][0]);
                acc[m][1] = fmaf(sm, w0a.y, acc[m][1]);
                acc[m][2] = fmaf(sm, w0a.z, acc[m][2]);
                acc[m][3] = fmaf(sm, w0a.w, acc[m][3]);
                acc[m][4] = fmaf(sm, w0b.x, acc[m][4]);
                acc[m][5] = fmaf(sm, w0b.y, acc[m][5]);
                acc[m][6] = fmaf(sm, w0b.z, acc[m][6]);
                acc[m][7] = fmaf(sm, w0b.w, acc[m][7]);
            }
            // odd k
            #pragma unroll
            for (int m = 0; m < 16; ++m) {
                const float sm = ((ms[m] >> (2 * kp + 1)) & 1u) ? 1.0f : 0.0f;
                acc[m][0] = fmaf(sm, w1a.x, acc[m][0]);
                acc[m][1] = fmaf(sm, w1a.y, acc[m][1]);
                acc[m][2] = fmaf(sm, w1a.z, acc[m][2]);
                acc[m][3] = fmaf(sm, w1a.w, acc[m][3]);
                acc[m][4] = fmaf(sm, w1b.x, acc[m][4]);
                acc[m][5] = fmaf(sm, w1b.y, acc[m][5]);
                acc[m][6] = fmaf(sm, w1b.z, acc[m][6]);
                acc[m][7] = fmaf(sm, w1b.w, acc[m][7]);
            }
            w0a = n0a; w0b = n0b; w1a = n1a; w1b = n1b;
        }
    }

    // ---- fused LIF epilogue (round-7 verbatim, 16 rows) ----
    float4 bva = ((const float4*)(bias + cb))[0];
    float4 bvb = ((const float4*)(bias + cb))[1];
    float bv[8] = {bva.x, bva.y, bva.z, bva.w, bvb.x, bvb.y, bvb.z, bvb.w};

    uint32_t pk[16];
    #pragma unroll
    for (int m = 0; m < 16; ++m) {
        const size_t row = (size_t)(r0 + m) * N_SZ + cb;
        float v[8];
        #pragma unroll
        for (int j = 0; j < 8; ++j) v[j] = acc[m][j] + bv[j];
        if (ADD_U) {
            const float4 ua = ((const float4*)(u_prev + row))[0];
            const float4 ub = ((const float4*)(u_prev + row))[1];
            v[0] += ua.x; v[1] += ua.y; v[2] += ua.z; v[3] += ua.w;
            v[4] += ub.x; v[5] += ub.y; v[6] += ub.z; v[7] += ub.w;
        }
        if (ADD_X1) {
            const float4 xa = ((const float4*)(x1 + row))[0];
            const float4 xb = ((const float4*)(x1 + row))[1];
            v[0] += xa.x; v[1] += xa.y; v[2] += xa.z; v[3] += xa.w;
            v[4] += xb.x; v[5] += xb.y; v[6] += xb.z; v[7] += xb.w;
        }
        float un[8], sv[8];
        #pragma unroll
        for (int j = 0; j < 8; ++j) {
            sv[j] = (v[j] >= 1.0f) ? 1.0f : 0.0f;
            un[j] = (v[j] - 2.0f * sv[j]) * LEAKY;
        }
        ((float4*)(u_out + row))[0] = (float4){un[0], un[1], un[2], un[3]};
        ((float4*)(u_out + row))[1] = (float4){un[4], un[5], un[6], un[7]};
        if (AMODE == 1) {
            ((float4*)(a_ptr + row))[0] = (float4){sv[0], sv[1], sv[2], sv[3]};
            ((float4*)(a_ptr + row))[1] = (float4){sv[4], sv[5], sv[6], sv[7]};
        } else if (AMODE == 2) {
            const float4 aa = ((const float4*)(a_ptr + row))[0];
            const float4 ab = ((const float4*)(a_ptr + row))[1];
            ((float4*)(a_ptr + row))[0] = (float4){aa.x * LEAKY + sv[0], aa.y * LEAKY + sv[1],
                                                   aa.z * LEAKY + sv[2], aa.w * LEAKY + sv[3]};
            ((float4*)(a_ptr + row))[1] = (float4){ab.x * LEAKY + sv[4], ab.y * LEAKY + sv[5],
                                                   ab.z * LEAKY + sv[6], ab.w * LEAKY + sv[7]};
        }
        unsigned long long bal[8];
        #pragma unroll
        for (int j = 0; j < 8; ++j) bal[j] = __ballot(v[j] >= 1.0f);
        pk[m] = mask_word(bal, lane);
    }
    if (lane < 16) {
        uint32_t* mp = mOut + (size_t)lane * B_SZ + r0;
        ((uint4*)mp)[0] = (uint4){pk[0],  pk[1],  pk[2],  pk[3]};
        ((uint4*)mp)[1] = (uint4){pk[4],  pk[5],  pk[6],  pk[7]};
        ((uint4*)mp)[2] = (uint4){pk[8],  pk[9],  pk[10], pk[11]};
        ((uint4*)mp)[3] = (uint4){pk[12], pk[13], pk[14], pk[15]};
    }
}

// ---------------------------------------------------------------------------
__global__ void mask_build(const uint16_t* __restrict__ s, uint32_t* __restrict__ mOut) {
    const int lane = threadIdx.x & 63;
    const int w    = threadIdx.x >> 6;
    const int r0   = blockIdx.x * 32 + w * 8;
    const int cb   = lane * 8;
    uint32_t pk[8];
    #pragma unroll
    for (int m = 0; m < 8; ++m) {
        const ushort4 sa = ((const ushort4*)(s + (size_t)(r0 + m) * N_SZ + cb))[0];
        const ushort4 sb = ((const ushort4*)(s + (size_t)(r0 + m) * N_SZ + cb))[1];
        const uint16_t sv[8] = {sa.x, sa.y, sa.z, sa.w, sb.x, sb.y, sb.z, sb.w};
        unsigned long long bal[8];
        #pragma unroll
        for (int j = 0; j < 8; ++j) bal[j] = __ballot(sv[j] != 0);
        pk[m] = mask_word(bal, lane);
    }
    if (lane < 16) {
        uint32_t* mp = mOut + (size_t)lane * B_SZ + r0;
        ((uint4*)mp)[0] = (uint4){pk[0], pk[1], pk[2], pk[3]};
        ((uint4*)mp)[1] = (uint4){pk[4], pk[5], pk[6], pk[7]};
    }
}

// ---------------------------------------------------------------------------
// f32 vector GEMM for the first (continuous-x) GEMM — round-1 math verbatim.
#define BM 128
#define BN 128
#define BK 16
#define TM 8
#define TN 8
#define PAD 4

__global__ __launch_bounds__(256, 2)
void gemm0_lif(const float* __restrict__ A, const float* __restrict__ W,
               const float* __restrict__ bias, float* __restrict__ u_out,
               uint16_t* __restrict__ s_out, float* __restrict__ a_ptr,
               float* __restrict__ c_out) {
    __shared__ float As[BK][BM + PAD];
    __shared__ float Bs[BK][BN + PAD];
    const int tid = threadIdx.x;
    const int tx = tid & 15, ty = tid >> 4;
    const int m0 = blockIdx.y * BM, n0 = blockIdx.x * BN;
    float acc[TM][TN];
    #pragma unroll
    for (int i = 0; i < TM; ++i)
        #pragma unroll
        for (int j = 0; j < TN; ++j) acc[i][j] = 0.f;
    const int lr = tid >> 2, lc = (tid & 3) * 4;
    for (int k0 = 0; k0 < K_SZ; k0 += BK) {
        #pragma unroll
        for (int h = 0; h < 2; ++h) {
            const int r = lr + h * 64;
            const float4 v = *(const float4*)(A + (size_t)(m0 + r) * K_SZ + k0 + lc);
            As[lc + 0][r] = v.x; As[lc + 1][r] = v.y;
            As[lc + 2][r] = v.z; As[lc + 3][r] = v.w;
        }
        #pragma unroll
        for (int h = 0; h < 2; ++h) {
            const int r = lr + h * 64;
            const float4 v = *(const float4*)(W + (size_t)(n0 + r) * K_SZ + k0 + lc);
            Bs[lc + 0][r] = v.x; Bs[lc + 1][r] = v.y;
            Bs[lc + 2][r] = v.z; Bs[lc + 3][r] = v.w;
        }
        __syncthreads();
        #pragma unroll
        for (int kk = 0; kk < BK; ++kk) {
            float av[TM], bvv[TN];
            #pragma unroll
            for (int i = 0; i < TM; ++i) av[i] = As[kk][ty * TM + i];
            #pragma unroll
            for (int j = 0; j < TN; ++j) bvv[j] = Bs[kk][tx * TN + j];
            #pragma unroll
            for (int i = 0; i < TM; ++i)
                #pragma unroll
                for (int j = 0; j < TN; ++j)
                    acc[i][j] = fmaf(av[i], bvv[j], acc[i][j]);
        }
        __syncthreads();
    }
    #pragma unroll
    for (int i = 0; i < TM; ++i) {
        const size_t row = (size_t)(m0 + ty * TM + i) * N_SZ + n0 + tx * TN;
        #pragma unroll
        for (int j = 0; j < TN; ++j) {
            const float v = acc[i][j] + bias[n0 + tx * TN + j];
            c_out[row + j] = v;
            const float sv = (v >= 1.0f) ? 1.0f : 0.0f;
            u_out[row + j] = (v - 2.0f * sv) * LEAKY;
            s_out[row + j] = (v >= 1.0f) ? (uint16_t)0x3F80 : (uint16_t)0;
            a_ptr[row + j] = sv;
        }
    }
}

// ---------------- 512x512 transpose (exact copy) ----------------
__global__ void transpose512(const float* __restrict__ in, float* __restrict__ out) {
    __shared__ float t[32][33];
    const int mat = blockIdx.z;
    const int bx = blockIdx.x * 32, by = blockIdx.y * 32;
    const int x = threadIdx.x & 31, yg = threadIdx.x >> 5;
    const float* I = in + (size_t)mat * N_SZ * K_SZ;
    float* O = out + (size_t)mat * N_SZ * K_SZ;
    #pragma unroll
    for (int i = 0; i < 4; ++i)
        t[yg * 4 + i][x] = I[(size_t)(by + yg * 4 + i) * 512 + bx + x];
    __syncthreads();
    #pragma unroll
    for (int i = 0; i < 4; ++i)
        O[(size_t)(bx + yg * 4 + i) * 512 + by + x] = t[x][yg * 4 + i];
}

__global__ void scale_kernel(float* __restrict__ p, float inv, int n4) {
    int i = blockIdx.x * blockDim.x + threadIdx.x;
    const int stride = gridDim.x * blockDim.x;
    for (; i < n4; i += stride) {
        float4 v = ((float4*)p)[i];
        v.x *= inv; v.y *= inv; v.z *= inv; v.w *= inv;
        ((float4*)p)[i] = v;
    }
}

extern "C" void kernel_launch(void* const* d_in, const int* in_sizes, int n_in,
                              void* d_out, int out_size, void* d_ws, size_t ws_size,
                              hipStream_t stream) {
    const float* x  = (const float*)d_in[0];
    const float* Wx = (const float*)d_in[1];
    const float* bx = (const float*)d_in[2];
    const float* Ws = (const float*)d_in[3];
    const float* bs = (const float*)d_in[4];
    // d_in[5] = time_step -> hardcoded 32

    const size_t BNt = (size_t)B_SZ * N_SZ;
    const size_t NK  = (size_t)N_SZ * K_SZ;
    const size_t MSZ = (size_t)16 * B_SZ;

    float*    u   = (float*)d_ws;                  // [3][B][N] f32
    float*    x1  = u + 3 * BNt;                   // [B][N] f32
    uint16_t* s0b = (uint16_t*)(x1 + BNt);         // [B][N] bf16
    float*    WsT = (float*)(s0b + BNt);           // [3][512][512]
    uint32_t* mT  = (uint32_t*)(WsT + 3 * NK + 4096); // 16KB prefetch slack
    uint32_t* mT0 = mT;
    uint32_t* mT1 = mT + MSZ;
    uint32_t* mT2 = mT + 2 * MSZ;

    float* a0 = (float*)d_out;
    float* a2 = a0 + BNt;
    float* u0 = u; float* u1 = u + BNt; float* u2 = u + 2 * BNt;

    dim3 blk(256);
    dim3 gridV(N_SZ / BN, B_SZ / BM);   // gemm0: (4, 128)
    dim3 gridR(B_SZ / 64);              // rowgemm: 256 blocks (64 rows each)
    dim3 gridM(B_SZ / 32);              // mask_build: 512
    dim3 gridT(16, 16, 3);

    // ---- prep ----
    transpose512<<<gridT, blk, 0, stream>>>(Ws, WsT);

    // ---- t = 0 ----
    gemm0_lif<<<gridV, blk, 0, stream>>>(x, Wx, bx, u0, s0b, a0, x1);
    mask_build<<<gridM, blk, 0, stream>>>(s0b, mT0);
    rowgemm_lif<0, false, false><<<gridR, blk, 0, stream>>>(
        mT0, WsT, bs, nullptr, nullptr, u1, mT1, nullptr);
    rowgemm_lif<1, false, false><<<gridR, blk, 0, stream>>>(
        mT1, WsT + NK, bs + N_SZ, nullptr, nullptr, u2, mT2, a2);

    // ---- t = 1 .. T-1 ----
    for (int t = 1; t < T_STEPS; ++t) {
        rowgemm_lif<2, true, true><<<gridR, blk, 0, stream>>>(
            mT2, WsT + 2 * NK, bs + 2 * N_SZ, u0, x1, u0, mT0, a0);
        rowgemm_lif<0, true, false><<<gridR, blk, 0, stream>>>(
            mT0, WsT, bs, u1, nullptr, u1, mT1, nullptr);
        rowgemm_lif<2, true, false><<<gridR, blk, 0, stream>>>(
            mT1, WsT + NK, bs + N_SZ, u2, nullptr, u2, mT2, a2);
    }

    // ---- finalize: a /= (1 - 0.9^32)/0.1 ----
    double p = 1.0;
    for (int i = 0; i < T_STEPS; ++i) p *= 0.9;
    const float inv = (float)(1.0 / ((1.0 - p) / 0.1));
    scale_kernel<<<2048, blk, 0, stream>>>((float*)d_out, inv, (int)(2 * BNt / 4));
}

// Round 12
// 6364.923 us; speedup vs baseline: 2.9690x; 2.9690x over previous
//
#include <hip/hip_runtime.h>
#include <stdint.h>

// SNN LIF multi-layer, B=16384, D_IN=N=512, L=3, T=32 (T hardcoded).
//
// Round 12: SPARSE bitmask GEMM — skip non-fired k entirely (bit-exact:
// fmaf(0,w,acc)==acc, fmaf(1,w,acc)==acc+w, both exact in IEEE; ctz
// iteration preserves k-ascending chain order).
//  - W staged 16 k-rows at a time into double-buffered LDS via LINEAR
//    global_load_lds (contiguous per-lane sources — round 6's failure was
//    gapped sources); all lanes read row k as contiguous ds_read_b128
//    (round 9 measured 0 bank conflicts for this pattern).
//  - 1024-thread blocks, 16 waves (4/SIMD - latency hiding), wave = 8 rows
//    x 256-col half, acc[8][4]=32 VGPR (no spill risk).
//  - mask consumption: readlane per plane (proven); production: round-10
//    ballot/spread4 packing adapted to R=8 (derivation re-checked).
//  - epilogue op order verbatim from the round-1/5/10 PASS.

#define B_SZ 16384
#define N_SZ 512
#define K_SZ 512
#define T_STEPS 32
#define LEAKY 0.9f

#define CHUNK 16                    // k-rows per LDS buffer (32 KB each)

// ---------------------------------------------------------------------------
// spread 8 bits b7..b0 to bit positions 0,4,8,...,28
__device__ inline uint32_t spread4(uint32_t b) {
    b = (b | (b << 12)) & 0x000F000Fu;
    b = (b | (b << 6))  & 0x03030303u;
    b = (b | (b << 3))  & 0x11111111u;
    return b;
}

// round-5 mask assembly (8 cols/lane) for mask_build only
__device__ inline uint32_t mask_word8(const unsigned long long bal[8], int lane) {
    const uint32_t sh = (4u * (uint32_t)lane) & 31u;
    uint32_t word = 0;
    #pragma unroll
    for (int j = 0; j < 8; ++j) {
        const uint32_t half = (lane < 8) ? (uint32_t)bal[j] : (uint32_t)(bal[j] >> 32);
        const uint32_t nib  = (half >> sh) & 0xFu;
        word |= ((nib * 0x00204081u) & 0x01010101u) << j;
    }
    return word;
}

// ---------------------------------------------------------------------------
// AMODE: 0 = none, 1 = a := s, 2 = a := a*LEAKY + s
template<int AMODE, bool ADD_U, bool ADD_X1>
__global__ __launch_bounds__(1024, 1)
void spgemm_lif(const uint32_t* __restrict__ mIn,  // [16][B] spike bit-planes
                const float* __restrict__ Wt,      // [512 k][512 n] = W.T
                const float* __restrict__ bias,
                const float* u_prev,               // may alias u_out
                const float* __restrict__ x1,
                float* u_out,
                uint32_t* __restrict__ mOut,       // [16][B] out bit-planes
                float* a_ptr)
{
    __shared__ float Wl[2][CHUNK * 512];           // 2 x 32 KB

    const int tid  = threadIdx.x;
    const int lane = tid & 63;
    const int w    = tid >> 6;                     // 0..15
    const int rg   = w >> 1;                       // row group 0..7
    const int g    = w & 1;                        // column half
    const int r0   = blockIdx.x * 64 + rg * 8;     // 8 rows per wave
    const int cb   = g * 256 + lane * 4;           // 4-col stripe per lane

    float acc[8][4];
    #pragma unroll
    for (int m = 0; m < 8; ++m)
        #pragma unroll
        for (int j = 0; j < 4; ++j) acc[m][j] = 0.f;

    // linear chunk copy: 32 KB = 32 segments of 1 KB = 16 waves x 2 instr
    auto stage = [&](int c, int bf) {
        const float* src = Wt + (size_t)c * (CHUNK * 512);
        #pragma unroll
        for (int i = 0; i < 2; ++i) {
            const int seg = w * 2 + i;
            __builtin_amdgcn_global_load_lds(
                (const __attribute__((address_space(1))) unsigned int*)
                    (src + seg * 256 + lane * 4),                 // per-lane src
                (__attribute__((address_space(3))) unsigned int*)
                    (&Wl[bf][seg * 256]),                         // uniform dst
                16, 0, 0);
        }
    };

    // sparse compute: iterate set bits (ascending k) of each row's 16-bit word
    auto compute = [&](int bf, const uint32_t* msr, int sh) {
        const float* base = &Wl[bf][0];
        #pragma unroll
        for (int m = 0; m < 8; ++m) {
            uint32_t wrd = (msr[m] >> sh) & 0xFFFFu;
            while (wrd) {
                const int kk = __builtin_ctz(wrd);
                wrd &= wrd - 1u;
                const float4 wv = *(const float4*)(base + kk * 512 + cb);
                acc[m][0] += wv.x;
                acc[m][1] += wv.y;
                acc[m][2] += wv.z;
                acc[m][3] += wv.w;
            }
        }
    };

    // ---- prologue ----
    uint32_t mv = mIn[r0 + (lane & 7)];            // rows in lanes 0..7
    stage(0, 0);
    __syncthreads();                               // drains DMA (vmcnt in barrier)

    // ---- main loop: 32 chunks of 16 k, k ascending ----
    int cur = 0;
    uint32_t msr[8];
    for (int c = 0; c < 32; ++c) {
        if (c + 1 < 32) stage(c + 1, cur ^ 1);
        if ((c & 1) == 0) {
            #pragma unroll
            for (int m = 0; m < 8; ++m)
                msr[m] = __builtin_amdgcn_readlane(mv, m);
            const int pn = (c >> 1) + 1;
            if (pn < 16) mv = mIn[(size_t)pn * B_SZ + r0 + (lane & 7)];
        }
        compute(cur, msr, (c & 1) * 16);
        __syncthreads();                           // all reads done + DMA landed
        cur ^= 1;
    }

    // ---- fused LIF epilogue (round-10 ops, R=8) ----
    const float4 bv = *(const float4*)(bias + cb);
    const int msel = lane & 7;
    unsigned long long balsel[4] = {0ull, 0ull, 0ull, 0ull};

    #pragma unroll
    for (int m = 0; m < 8; ++m) {
        const size_t row = (size_t)(r0 + m) * N_SZ + cb;
        float v[4];
        v[0] = acc[m][0] + bv.x; v[1] = acc[m][1] + bv.y;
        v[2] = acc[m][2] + bv.z; v[3] = acc[m][3] + bv.w;
        if (ADD_U) {
            const float4 ua = *(const float4*)(u_prev + row);
            v[0] += ua.x; v[1] += ua.y; v[2] += ua.z; v[3] += ua.w;
        }
        if (ADD_X1) {
            const float4 xa = *(const float4*)(x1 + row);
            v[0] += xa.x; v[1] += xa.y; v[2] += xa.z; v[3] += xa.w;
        }
        float un[4], sv[4];
        #pragma unroll
        for (int j = 0; j < 4; ++j) {
            sv[j] = (v[j] >= 1.0f) ? 1.0f : 0.0f;
            un[j] = (v[j] - 2.0f * sv[j]) * LEAKY;
        }
        *(float4*)(u_out + row) = (float4){un[0], un[1], un[2], un[3]};
        if (AMODE == 1) {
            *(float4*)(a_ptr + row) = (float4){sv[0], sv[1], sv[2], sv[3]};
        } else if (AMODE == 2) {
            const float4 aa = *(const float4*)(a_ptr + row);
            *(float4*)(a_ptr + row) = (float4){aa.x * LEAKY + sv[0], aa.y * LEAKY + sv[1],
                                               aa.z * LEAKY + sv[2], aa.w * LEAKY + sv[3]};
        }
        // ballot bit L of bal[j] = spike(row m, col g*256 + 4L + j)
        unsigned long long bal[4];
        #pragma unroll
        for (int j = 0; j < 4; ++j) bal[j] = __ballot(v[j] >= 1.0f);
        #pragma unroll
        for (int j = 0; j < 4; ++j)
            balsel[j] = (m == msel) ? bal[j] : balsel[j];
    }

    // lane (h = lane>>3, msel) packs plane p = g*8 + h for row r0+msel:
    // word bit t=4i+j <- bit (8h+i) of bal[j]  (col 32h+4i+j within half)
    const int h = lane >> 3;
    uint32_t pk = 0;
    #pragma unroll
    for (int j = 0; j < 4; ++j)
        pk |= spread4((uint32_t)(balsel[j] >> (8 * h)) & 0xFFu) << j;
    mOut[(size_t)(g * 8 + h) * B_SZ + r0 + msel] = pk;
}

// ---------------------------------------------------------------------------
// bitmask from bf16 spikes (for s0 produced by gemm0) — round-5 verbatim
__global__ void mask_build(const uint16_t* __restrict__ s, uint32_t* __restrict__ mOut) {
    const int lane = threadIdx.x & 63;
    const int w    = threadIdx.x >> 6;
    const int r0   = blockIdx.x * 32 + w * 8;
    const int cb   = lane * 8;
    uint32_t pk[8];
    #pragma unroll
    for (int m = 0; m < 8; ++m) {
        const ushort4 sa = ((const ushort4*)(s + (size_t)(r0 + m) * N_SZ + cb))[0];
        const ushort4 sb = ((const ushort4*)(s + (size_t)(r0 + m) * N_SZ + cb))[1];
        const uint16_t sv[8] = {sa.x, sa.y, sa.z, sa.w, sb.x, sb.y, sb.z, sb.w};
        unsigned long long bal[8];
        #pragma unroll
        for (int j = 0; j < 8; ++j) bal[j] = __ballot(sv[j] != 0);
        pk[m] = mask_word8(bal, lane);
    }
    if (lane < 16) {
        uint32_t* mp = mOut + (size_t)lane * B_SZ + r0;
        ((uint4*)mp)[0] = (uint4){pk[0], pk[1], pk[2], pk[3]};
        ((uint4*)mp)[1] = (uint4){pk[4], pk[5], pk[6], pk[7]};
    }
}

// ---------------------------------------------------------------------------
// f32 vector GEMM for the first (continuous-x) GEMM — round-1 math verbatim.
#define BM 128
#define BN 128
#define BK 16
#define TM 8
#define TN 8
#define PAD 4

__global__ __launch_bounds__(256, 2)
void gemm0_lif(const float* __restrict__ A, const float* __restrict__ W,
               const float* __restrict__ bias, float* __restrict__ u_out,
               uint16_t* __restrict__ s_out, float* __restrict__ a_ptr,
               float* __restrict__ c_out) {
    __shared__ float As[BK][BM + PAD];
    __shared__ float Bs[BK][BN + PAD];
    const int tid = threadIdx.x;
    const int tx = tid & 15, ty = tid >> 4;
    const int m0 = blockIdx.y * BM, n0 = blockIdx.x * BN;
    float acc[TM][TN];
    #pragma unroll
    for (int i = 0; i < TM; ++i)
        #pragma unroll
        for (int j = 0; j < TN; ++j) acc[i][j] = 0.f;
    const int lr = tid >> 2, lc = (tid & 3) * 4;
    for (int k0 = 0; k0 < K_SZ; k0 += BK) {
        #pragma unroll
        for (int h = 0; h < 2; ++h) {
            const int r = lr + h * 64;
            const float4 v = *(const float4*)(A + (size_t)(m0 + r) * K_SZ + k0 + lc);
            As[lc + 0][r] = v.x; As[lc + 1][r] = v.y;
            As[lc + 2][r] = v.z; As[lc + 3][r] = v.w;
        }
        #pragma unroll
        for (int h = 0; h < 2; ++h) {
            const int r = lr + h * 64;
            const float4 v = *(const float4*)(W + (size_t)(n0 + r) * K_SZ + k0 + lc);
            Bs[lc + 0][r] = v.x; Bs[lc + 1][r] = v.y;
            Bs[lc + 2][r] = v.z; Bs[lc + 3][r] = v.w;
        }
        __syncthreads();
        #pragma unroll
        for (int kk = 0; kk < BK; ++kk) {
            float av[TM], bvv[TN];
            #pragma unroll
            for (int i = 0; i < TM; ++i) av[i] = As[kk][ty * TM + i];
            #pragma unroll
            for (int j = 0; j < TN; ++j) bvv[j] = Bs[kk][tx * TN + j];
            #pragma unroll
            for (int i = 0; i < TM; ++i)
                #pragma unroll
                for (int j = 0; j < TN; ++j)
                    acc[i][j] = fmaf(av[i], bvv[j], acc[i][j]);
        }
        __syncthreads();
    }
    #pragma unroll
    for (int i = 0; i < TM; ++i) {
        const size_t row = (size_t)(m0 + ty * TM + i) * N_SZ + n0 + tx * TN;
        #pragma unroll
        for (int j = 0; j < TN; ++j) {
            const float v = acc[i][j] + bias[n0 + tx * TN + j];
            c_out[row + j] = v;
            const float sv = (v >= 1.0f) ? 1.0f : 0.0f;
            u_out[row + j] = (v - 2.0f * sv) * LEAKY;
            s_out[row + j] = (v >= 1.0f) ? (uint16_t)0x3F80 : (uint16_t)0;
            a_ptr[row + j] = sv;
        }
    }
}

// ---------------- 512x512 transpose (exact copy) ----------------
__global__ void transpose512(const float* __restrict__ in, float* __restrict__ out) {
    __shared__ float t[32][33];
    const int mat = blockIdx.z;
    const int bx = blockIdx.x * 32, by = blockIdx.y * 32;
    const int x = threadIdx.x & 31, yg = threadIdx.x >> 5;
    const float* I = in + (size_t)mat * N_SZ * K_SZ;
    float* O = out + (size_t)mat * N_SZ * K_SZ;
    #pragma unroll
    for (int i = 0; i < 4; ++i)
        t[yg * 4 + i][x] = I[(size_t)(by + yg * 4 + i) * 512 + bx + x];
    __syncthreads();
    #pragma unroll
    for (int i = 0; i < 4; ++i)
        O[(size_t)(bx + yg * 4 + i) * 512 + by + x] = t[x][yg * 4 + i];
}

__global__ void scale_kernel(float* __restrict__ p, float inv, int n4) {
    int i = blockIdx.x * blockDim.x + threadIdx.x;
    const int stride = gridDim.x * blockDim.x;
    for (; i < n4; i += stride) {
        float4 v = ((float4*)p)[i];
        v.x *= inv; v.y *= inv; v.z *= inv; v.w *= inv;
        ((float4*)p)[i] = v;
    }
}

extern "C" void kernel_launch(void* const* d_in, const int* in_sizes, int n_in,
                              void* d_out, int out_size, void* d_ws, size_t ws_size,
                              hipStream_t stream) {
    const float* x  = (const float*)d_in[0];
    const float* Wx = (const float*)d_in[1];
    const float* bx = (const float*)d_in[2];
    const float* Ws = (const float*)d_in[3];
    const float* bs = (const float*)d_in[4];
    // d_in[5] = time_step -> hardcoded 32

    const size_t BNt = (size_t)B_SZ * N_SZ;
    const size_t NK  = (size_t)N_SZ * K_SZ;
    const size_t MSZ = (size_t)16 * B_SZ;

    float*    u   = (float*)d_ws;                  // [3][B][N] f32
    float*    x1  = u + 3 * BNt;                   // [B][N] f32
    uint16_t* s0b = (uint16_t*)(x1 + BNt);         // [B][N] bf16
    float*    WsT = (float*)(s0b + BNt);           // [3][512][512]
    uint32_t* mT  = (uint32_t*)(WsT + 3 * NK + 4096);
    uint32_t* mT0 = mT;
    uint32_t* mT1 = mT + MSZ;
    uint32_t* mT2 = mT + 2 * MSZ;

    float* a0 = (float*)d_out;
    float* a2 = a0 + BNt;
    float* u0 = u; float* u1 = u + BNt; float* u2 = u + 2 * BNt;

    dim3 blkS(1024);
    dim3 blk(256);
    dim3 gridV(N_SZ / BN, B_SZ / BM);   // gemm0: (4, 128)
    dim3 gridS(B_SZ / 64);              // spgemm: 256 blocks (64 rows each)
    dim3 gridM(B_SZ / 32);              // mask_build: 512
    dim3 gridT(16, 16, 3);

    // ---- prep ----
    transpose512<<<gridT, blk, 0, stream>>>(Ws, WsT);

    // ---- t = 0 ----
    gemm0_lif<<<gridV, blk, 0, stream>>>(x, Wx, bx, u0, s0b, a0, x1);
    mask_build<<<gridM, blk, 0, stream>>>(s0b, mT0);
    spgemm_lif<0, false, false><<<gridS, blkS, 0, stream>>>(
        mT0, WsT, bs, nullptr, nullptr, u1, mT1, nullptr);
    spgemm_lif<1, false, false><<<gridS, blkS, 0, stream>>>(
        mT1, WsT + NK, bs + N_SZ, nullptr, nullptr, u2, mT2, a2);

    // ---- t = 1 .. T-1 ----
    for (int t = 1; t < T_STEPS; ++t) {
        spgemm_lif<2, true, true><<<gridS, blkS, 0, stream>>>(
            mT2, WsT + 2 * NK, bs + 2 * N_SZ, u0, x1, u0, mT0, a0);
        spgemm_lif<0, true, false><<<gridS, blkS, 0, stream>>>(
            mT0, WsT, bs, u1, nullptr, u1, mT1, nullptr);
        spgemm_lif<2, true, false><<<gridS, blkS, 0, stream>>>(
            mT1, WsT + NK, bs + N_SZ, u2, nullptr, u2, mT2, a2);
    }

    // ---- finalize: a /= (1 - 0.9^32)/0.1 ----
    double p = 1.0;
    for (int i = 0; i < T_STEPS; ++i) p *= 0.9;
    const float inv = (float)(1.0 / ((1.0 - p) / 0.1));
    scale_kernel<<<2048, blk, 0, stream>>>((float*)d_out, inv, (int)(2 * BNt / 4));
}